// Round 5
// baseline (1698.485 us; speedup 1.0000x reference)
//
#include <hip/hip_runtime.h>
#include <math.h>

#define D_   4096
#define N_   16384               // 8*2048 rows
#define TOT  67108864ULL         // N_*D_
#define KSEL 8304721u            // int(8388608*0.99), 1-indexed kth smallest

// ---------------- static device scratch ----------------
__device__ unsigned long long g_colsum[D_];     // fixed-point 2^32 column |x| sums
__device__ unsigned int  g_hist[2048];
__device__ unsigned int  g_state[2];            // {krem, prefix}
__device__ float         g_outliner;
__device__ unsigned int  g_maxbits;
__device__ float         g_scale;
__device__ unsigned char g_mask[D_];
__device__ float g_omega[D_ * 16];
__device__ float g_tall [N_ * 16];              // Y0 -> Q0 -> Y2 -> Q2 -> Y4
__device__ float g_small[D_ * 16];              // Y1 -> Q1 -> Y3 -> Q3 -> W -> Z
__device__ float g_gpart[64 * 256];
__device__ float g_M[256];                      // L^-1 or G^-1 (fp32)

// ---------------- helpers ----------------
__device__ __forceinline__ unsigned rotl32(unsigned v, int s) { return (v << s) | (v >> (32 - s)); }

__device__ __forceinline__ float erfinv32(float xx) {   // XLA/Giles ErfInv32 polynomial
  float w = -log1pf(-xx * xx);
  float p;
  if (w < 5.f) {
    w -= 2.5f;
    p = 2.81022636e-08f;
    p = fmaf(p, w, 3.43273939e-07f);
    p = fmaf(p, w, -3.5233877e-06f);
    p = fmaf(p, w, -4.39150654e-06f);
    p = fmaf(p, w, 0.00021858087f);
    p = fmaf(p, w, -0.00125372503f);
    p = fmaf(p, w, -0.00417768164f);
    p = fmaf(p, w, 0.246640727f);
    p = fmaf(p, w, 1.50140941f);
  } else {
    w = sqrtf(w) - 3.f;
    p = -0.000200214257f;
    p = fmaf(p, w, 0.000100950558f);
    p = fmaf(p, w, 0.00134934322f);
    p = fmaf(p, w, -0.00367342844f);
    p = fmaf(p, w, 0.00573950773f);
    p = fmaf(p, w, -0.0076224613f);
    p = fmaf(p, w, 0.00943887047f);
    p = fmaf(p, w, 1.00167406f);
    p = fmaf(p, w, 2.83297682f);
  }
  return p * xx;
}

__device__ __forceinline__ float bits_to_normal(unsigned b) {
  float f = __uint_as_float((b >> 9) | 0x3f800000u) - 1.0f;
  float u = fmaf(f, 2.0f, -0.99999994f);
  u = fmaxf(-0.99999994f, u);
  return 1.41421356f * erfinv32(u);
}

__device__ __forceinline__ float gelu_exact(float v) {
  return 0.5f * v * (1.f + erff(v * 0.70710678f));
}

// ---------------- kernels ----------------
__global__ void k_init() {
  int t = threadIdx.x;
  for (int i = t; i < D_; i += 256) g_colsum[i] = 0ull;
  for (int i = t; i < 2048; i += 256) g_hist[i] = 0u;
  if (t == 0) { g_state[0] = KSEL; g_state[1] = 0u; g_maxbits = 0u; }
}

// pass1: gelu -> out0, fixed-point column sums, level-0 histogram of |x[0]|
__global__ __launch_bounds__(256) void k_pass1(const float* __restrict__ x, float* __restrict__ out0) {
  __shared__ unsigned lh[4 * 2056];             // 4 wave-private bank-shifted copies
  int t = threadIdx.x, b = blockIdx.x;
  bool doh = (b < 64);                      // blocks 0..63 cover rows 0..2047 = x[0]
  for (int i = t; i < 4 * 2056; i += 256) lh[i] = 0u;
  int cp = (t >> 6) * 2056;
  float acc[16];
#pragma unroll
  for (int j = 0; j < 16; ++j) acc[j] = 0.f;
  __syncthreads();
  const float4* xv = (const float4*)(x + (size_t)b * 131072);   // 32 rows
  float4* ov = (float4*)(out0 + (size_t)b * 131072);
  for (int i = 0; i < 128; i += 4) {
#pragma unroll
    for (int jj = 0; jj < 4; ++jj) {
      int f = t + 256 * (i + jj);
      float4 v = xv[f];
      float4 g;
      g.x = gelu_exact(v.x); g.y = gelu_exact(v.y); g.z = gelu_exact(v.z); g.w = gelu_exact(v.w);
      ov[f] = g;
      acc[jj * 4 + 0] += fabsf(v.x);
      acc[jj * 4 + 1] += fabsf(v.y);
      acc[jj * 4 + 2] += fabsf(v.z);
      acc[jj * 4 + 3] += fabsf(v.w);
      if (doh) {
        atomicAdd(&lh[cp + ((__float_as_uint(v.x) & 0x7fffffffu) >> 21)], 1u);
        atomicAdd(&lh[cp + ((__float_as_uint(v.y) & 0x7fffffffu) >> 21)], 1u);
        atomicAdd(&lh[cp + ((__float_as_uint(v.z) & 0x7fffffffu) >> 21)], 1u);
        atomicAdd(&lh[cp + ((__float_as_uint(v.w) & 0x7fffffffu) >> 21)], 1u);
      }
    }
  }
#pragma unroll
  for (int jj = 0; jj < 4; ++jj) {
    int c4 = t + 256 * jj;
#pragma unroll
    for (int k = 0; k < 4; ++k) {
      unsigned long long q = (unsigned long long)((double)acc[jj * 4 + k] * 4294967296.0 + 0.5);
      atomicAdd(&g_colsum[4 * c4 + k], q);
    }
  }
  if (doh) {
    __syncthreads();
    for (int i = t; i < 2048; i += 256) {
      unsigned c = lh[i] + lh[2056 + i] + lh[4112 + i] + lh[6168 + i];
      if (c) atomicAdd(&g_hist[i], c);
    }
  }
}

// radix-select refinement histograms over x[0] (level 1: mid 11 bits, level 2: low 10 bits)
__global__ __launch_bounds__(256) void k_histL(const float* __restrict__ x, int level) {
  __shared__ unsigned lh[2048];
  int t = threadIdx.x, b = blockIdx.x;
  for (int i = t; i < 2048; i += 256) lh[i] = 0u;
  __syncthreads();
  unsigned pre = g_state[1];
  const float4* xv = (const float4*)x;
  size_t base = (size_t)b * 16384;
  for (int i = 0; i < 64; ++i) {
    float4 v = xv[base + t + 256 * i];
    unsigned u;
#define HPROC(comp) \
    u = __float_as_uint(comp) & 0x7fffffffu; \
    if (level == 1) { if ((u >> 21) == (pre >> 21)) atomicAdd(&lh[(u >> 10) & 0x7ffu], 1u); } \
    else            { if ((u >> 10) == (pre >> 10)) atomicAdd(&lh[u & 0x3ffu], 1u); }
    HPROC(v.x) HPROC(v.y) HPROC(v.z) HPROC(v.w)
#undef HPROC
  }
  __syncthreads();
  for (int i = t; i < 2048; i += 256) { unsigned c = lh[i]; if (c) atomicAdd(&g_hist[i], c); }
}

__global__ void k_scan(int level, float* __restrict__ od) {
  __shared__ unsigned h[2048];
  __shared__ unsigned ps[256];
  int t = threadIdx.x;
  unsigned loc = 0;
#pragma unroll
  for (int i = 0; i < 8; ++i) { unsigned v = g_hist[t * 8 + i]; h[t * 8 + i] = v; loc += v; }
  ps[t] = loc;
  __syncthreads();
  if (t == 0) {
    unsigned krem = g_state[0], pre = g_state[1];
    unsigned cum = 0; int g = 0;
    for (; g < 255; ++g) { if (cum + ps[g] >= krem) break; cum += ps[g]; }
    int b = g * 8;
    for (; b < 2047; ++b) { if (cum + h[b] >= krem) break; cum += h[b]; }
    krem -= cum;
    if (level == 0)      pre = ((unsigned)b) << 21;
    else if (level == 1) pre |= ((unsigned)b) << 10;
    else { pre |= (unsigned)b; g_outliner = __uint_as_float(pre); od[0] = __uint_as_float(pre); }
    g_state[0] = krem; g_state[1] = pre;
  }
  __syncthreads();
  for (int i = t; i < 2048; i += 256) g_hist[i] = 0u;
}

// top-819 column threshold via in-LDS bitonic sort of the 4096 fixed-point sums
__global__ __launch_bounds__(1024) void k_colsel() {
  __shared__ unsigned long long s[4096];
  int t = threadIdx.x;
  for (int m = 0; m < 4; ++m) s[t + 1024 * m] = g_colsum[t + 1024 * m];
  __syncthreads();
  for (int k = 2; k <= 4096; k <<= 1) {
    for (int j = k >> 1; j > 0; j >>= 1) {
#pragma unroll
      for (int m = 0; m < 4; ++m) {
        int i = t + 1024 * m;
        int l = i ^ j;
        if (l > i) {
          unsigned long long a = s[i], c = s[l];
          bool up = ((i & k) == 0);
          if (up ? (a > c) : (a < c)) { s[i] = c; s[l] = a; }
        }
      }
      __syncthreads();
    }
  }
  unsigned long long T = s[4096 - 819];
  for (int m = 0; m < 4; ++m) { int i = t + 1024 * m; g_mask[i] = (g_colsum[i] >= T) ? 1 : 0; }
}

// omega = jax.random.normal(key(42), (4096,16)), partitionable threefry counter mode
__global__ void k_omega() {
  unsigned i = blockIdx.x * 256 + threadIdx.x;
  if (i >= 65536u) return;
  const unsigned ks0 = 0u, ks1 = 42u, ks2 = 0x1BD11BDAu ^ 42u;
  unsigned x0 = 0u + ks0;
  unsigned x1 = i  + ks1;
#define RND(r) { x0 += x1; x1 = rotl32(x1, r); x1 ^= x0; }
  RND(13) RND(15) RND(26) RND(6)   x0 += ks1; x1 += ks2 + 1u;
  RND(17) RND(29) RND(16) RND(24)  x0 += ks2; x1 += ks0 + 2u;
  RND(13) RND(15) RND(26) RND(6)   x0 += ks0; x1 += ks1 + 3u;
  RND(17) RND(29) RND(16) RND(24)  x0 += ks1; x1 += ks2 + 4u;
  RND(13) RND(15) RND(26) RND(6)   x0 += ks2; x1 += ks0 + 5u;
#undef RND
  g_omega[i] = bits_to_normal(x0 ^ x1);
}

// Y(g_tall) = A @ B (A = masked x on the fly; B = omega or g_small).
// grid 256 blocks x block 1024. Block owns rows blk*64..+63, full K.
// thread (r = t&63, ks = t>>6) accumulates its 256-col K-chunk; LDS reduce
// over the 16 ks; Y written directly — NO split-K partial round-trip.
__global__ __launch_bounds__(1024) void k_AB(const float* __restrict__ x, int bsel) {
  __shared__ float red[16 * 1024];              // [ks][r*16+q], 64 KB
  int t = threadIdx.x;
  int r = t & 63, ks = t >> 6;
  int row = blockIdx.x * 64 + r;
  const float* Bm = bsel ? g_small : g_omega;
  float thr = g_outliner;
  float acc[16];
#pragma unroll
  for (int q = 0; q < 16; ++q) acc[q] = 0.f;
  const float* xr = x + (size_t)row * D_ + ks * 256;
  const unsigned char* mrow = g_mask + ks * 256;
  const float* bb = Bm + (size_t)(ks * 256) * 16;
  for (int j4 = 0; j4 < 64; ++j4) {
    float4 v = *(const float4*)(xr + 4 * j4);
    uchar4 mk = *(const uchar4*)(mrow + 4 * j4);
    float a0 = (mk.x || fabsf(v.x) > thr) ? 0.f : v.x;
    float a1 = (mk.y || fabsf(v.y) > thr) ? 0.f : v.y;
    float a2 = (mk.z || fabsf(v.z) > thr) ? 0.f : v.z;
    float a3 = (mk.w || fabsf(v.w) > thr) ? 0.f : v.w;
    const float* b0 = bb + (size_t)(4 * j4) * 16;
#pragma unroll
    for (int q = 0; q < 16; ++q) {
      float s = acc[q];
      s = fmaf(a0, b0[q], s);
      s = fmaf(a1, b0[16 + q], s);
      s = fmaf(a2, b0[32 + q], s);
      s = fmaf(a3, b0[48 + q], s);
      acc[q] = s;
    }
  }
  float* rp = red + ks * 1024 + r * 16;
#pragma unroll
  for (int q4 = 0; q4 < 4; ++q4)
    *(float4*)(rp + 4 * q4) = make_float4(acc[4*q4], acc[4*q4+1], acc[4*q4+2], acc[4*q4+3]);
  __syncthreads();
  int rr = t >> 4, qq = t & 15;
  float s = 0.f;
  for (int k2 = 0; k2 < 16; ++k2) s += red[k2 * 1024 + rr * 16 + qq];
  g_tall[(size_t)(blockIdx.x * 64 + rr) * 16 + qq] = s;
}

// Yt(g_small) = A^T @ B (B = g_tall). grid 256 blocks x block 1024.
// Block owns cols blk*16..+15, all rows. thread (c = t&15, rs = t>>4)
// accumulates rows rs*256..+255; LDS reduce over the 64 rs. No partials.
__global__ __launch_bounds__(1024) void k_AtB(const float* __restrict__ x, int do_max) {
  __shared__ float red[64 * 256];               // [rs][c*16+q], 64 KB
  int t = threadIdx.x;
  int c = t & 15, rs = t >> 4;
  int c0 = blockIdx.x * 16;
  float thr = g_outliner;
  unsigned char mk = g_mask[c0 + c];
  float acc[16];
#pragma unroll
  for (int q = 0; q < 16; ++q) acc[q] = 0.f;
  float mx = 0.f;
  size_t rowbase = (size_t)rs * 256;
  for (int i = 0; i < 256; ++i) {
    size_t row = rowbase + i;
    float v = x[row * D_ + c0 + c];
    float av = fabsf(v);
    float a = (mk || av > thr) ? 0.f : v;
    if (do_max) { if (mk && av <= thr) mx = fmaxf(mx, av); }
    const float* br = g_tall + row * 16;
#pragma unroll
    for (int q = 0; q < 16; ++q) acc[q] = fmaf(a, br[q], acc[q]);
  }
  float* rp = red + rs * 256 + c * 16;
#pragma unroll
  for (int q4 = 0; q4 < 4; ++q4)
    *(float4*)(rp + 4 * q4) = make_float4(acc[4*q4], acc[4*q4+1], acc[4*q4+2], acc[4*q4+3]);
  if (do_max) {
#pragma unroll
    for (int off = 32; off > 0; off >>= 1) mx = fmaxf(mx, __shfl_xor(mx, off, 64));
    if ((t & 63) == 0) atomicMax(&g_maxbits, __float_as_uint(mx));
  }
  __syncthreads();
  if (t < 256) {
    int c2 = t >> 4, q2 = t & 15;
    float s = 0.f;
    for (int k2 = 0; k2 < 64; ++k2) s += red[k2 * 256 + c2 * 16 + q2];
    g_small[(size_t)(c0 + c2) * 16 + q2] = s;
  }
}

__global__ void k_scalewrite(float* __restrict__ od) {
  if (threadIdx.x == 0) {
    float s = __uint_as_float(g_maxbits) / 127.0f;
    g_scale = s; od[0] = s;
  }
}

// Gram partials: G = Y^T Y, block covers 256 rows; thread t <-> entry (t>>4, t&15)
__global__ __launch_bounds__(256) void k_gram(int which) {
  __shared__ float ys[1024];
  const float* Y = which ? g_small : g_tall;
  int t = threadIdx.x;
  int i = t >> 4, j = t & 15;
  float acc = 0.f;
  size_t row0 = (size_t)blockIdx.x * 256;
  for (int c = 0; c < 4; ++c) {
    ((float4*)ys)[t] = *(const float4*)(Y + (row0 + c * 64) * 16 + 4 * t);
    __syncthreads();
    for (int r = 0; r < 64; ++r) acc = fmaf(ys[r * 16 + i], ys[r * 16 + j], acc);
    __syncthreads();
  }
  g_gpart[blockIdx.x * 256 + t] = acc;
}

// combine Gram partials, Cholesky (fp64): mode 0 -> g_M = L^-1 ; mode 1 -> g_M = G^-1
__global__ void k_chol(int mode, int np) {
  __shared__ double G[256], L[256], M[256];
  int t = threadIdx.x;
  double s = 0.0;
  for (int p = 0; p < np; ++p) s += (double)g_gpart[p * 256 + t];
  G[t] = s; M[t] = 0.0; L[t] = 0.0;
  __syncthreads();
  for (int j = 0; j < 16; ++j) {
    if (t == j) {
      double d = G[j * 16 + j];
      for (int k = 0; k < j; ++k) d -= L[j * 16 + k] * L[j * 16 + k];
      L[j * 16 + j] = sqrt(d);
    }
    __syncthreads();
    if (t > j && t < 16) {
      double d = G[t * 16 + j];
      for (int k = 0; k < j; ++k) d -= L[t * 16 + k] * L[j * 16 + k];
      L[t * 16 + j] = d / L[j * 16 + j];
    }
    __syncthreads();
  }
  if (t < 16) {                      // column t of M = L^-1
    int jc = t;
    M[jc * 16 + jc] = 1.0 / L[jc * 16 + jc];
    for (int i2 = jc + 1; i2 < 16; ++i2) {
      double s2 = 0.0;
      for (int k = jc; k < i2; ++k) s2 += L[i2 * 16 + k] * M[k * 16 + jc];
      M[i2 * 16 + jc] = -s2 / L[i2 * 16 + i2];
    }
  }
  __syncthreads();
  if (mode == 0) g_M[t] = (float)M[t];
  else {
    int i2 = t >> 4, j2 = t & 15;
    double s2 = 0.0;
    for (int k = 0; k < 16; ++k) s2 += M[k * 16 + i2] * M[k * 16 + j2];
    g_M[t] = (float)s2;              // G^-1 = M^T M
  }
}

// Q = Y * L^-T in place: q[j] = sum_{i<=j} M[j][i]*y[i]
__global__ __launch_bounds__(256) void k_scaleQ(int which) {
  __shared__ float Mf[256];
  float* Y = which ? g_small : g_tall;
  int t = threadIdx.x;
  Mf[t] = g_M[t];
  __syncthreads();
  size_t row = (size_t)blockIdx.x * 256 + t;
  float4* yr = (float4*)(Y + row * 16);
  float4 v0 = yr[0], v1 = yr[1], v2 = yr[2], v3 = yr[3];
  float y[16] = {v0.x,v0.y,v0.z,v0.w, v1.x,v1.y,v1.z,v1.w, v2.x,v2.y,v2.z,v2.w, v3.x,v3.y,v3.z,v3.w};
  float q[16];
#pragma unroll
  for (int jq = 0; jq < 16; ++jq) {
    float s = 0.f;
    for (int iq = 0; iq <= jq; ++iq) s = fmaf(Mf[jq * 16 + iq], y[iq], s);
    q[jq] = s;
  }
  yr[0] = make_float4(q[0],q[1],q[2],q[3]);
  yr[1] = make_float4(q[4],q[5],q[6],q[7]);
  yr[2] = make_float4(q[8],q[9],q[10],q[11]);
  yr[3] = make_float4(q[12],q[13],q[14],q[15]);
}

// Z[d] = Ginv * W[d] in place in g_small
__global__ __launch_bounds__(256) void k_Zsolve() {
  __shared__ float Gf[256];
  int t = threadIdx.x;
  Gf[t] = g_M[t];
  __syncthreads();
  size_t d = (size_t)blockIdx.x * 256 + t;
  float4* wr = (float4*)(g_small + d * 16);
  float4 v0 = wr[0], v1 = wr[1], v2 = wr[2], v3 = wr[3];
  float w[16] = {v0.x,v0.y,v0.z,v0.w, v1.x,v1.y,v1.z,v1.w, v2.x,v2.y,v2.z,v2.w, v3.x,v3.y,v3.z,v3.w};
  float z[16];
#pragma unroll
  for (int jq = 0; jq < 16; ++jq) {
    float s = 0.f;
#pragma unroll
    for (int iq = 0; iq < 16; ++iq) s = fmaf(Gf[jq * 16 + iq], w[iq], s);
    z[jq] = s;
  }
  wr[0] = make_float4(z[0],z[1],z[2],z[3]);
  wr[1] = make_float4(z[4],z[5],z[6],z[7]);
  wr[2] = make_float4(z[8],z[9],z[10],z[11]);
  wr[3] = make_float4(z[12],z[13],z[14],z[15]);
}

// out1 = Y4 @ Z + outliers + quantized sub-outlier cols. grid (64 rowblocks, 8 col panels).
__global__ __launch_bounds__(256) void k_final(const float* __restrict__ x, float* __restrict__ out1) {
  __shared__ float zt[16 * 516];     // Z^T panel [q][512] staging (coalesced global load)
  int t = threadIdx.x;
  int rb = blockIdx.x, pn = blockIdx.y;
  int d0 = pn * 512;
  int row0 = rb * 256;
#pragma unroll
  for (int i = 0; i < 8; ++i) {
    int f = t + 256 * i;             // 0..2047
    int dd = f >> 2, q4 = f & 3;
    float4 zv = *(const float4*)(g_small + (size_t)(d0 + dd) * 16 + 4 * q4);
    zt[(4 * q4 + 0) * 516 + dd] = zv.x;
    zt[(4 * q4 + 1) * 516 + dd] = zv.y;
    zt[(4 * q4 + 2) * 516 + dd] = zv.z;
    zt[(4 * q4 + 3) * 516 + dd] = zv.w;
  }
  __syncthreads();
  float thr = g_outliner, sc = g_scale;
  int lf = t & 127;
  int half = t >> 7;
  int dl = 4 * lf;
  float4 zq[16];
#pragma unroll
  for (int q = 0; q < 16; ++q) zq[q] = *(const float4*)&zt[q * 516 + dl];
  uchar4 mk = *(const uchar4*)(g_mask + d0 + dl);
  for (int i = 0; i < 128; ++i) {
    int row = row0 + 2 * i + half;
    int rowu = __builtin_amdgcn_readfirstlane(row);   // wave-uniform by construction
    const float* yr = g_tall + (size_t)rowu * 16;
    float4 v = *(const float4*)(x + (size_t)rowu * D_ + d0 + dl);
    float4 a = make_float4(0.f, 0.f, 0.f, 0.f);
#pragma unroll
    for (int q = 0; q < 16; ++q) {
      float yq = yr[q];
      a.x = fmaf(yq, zq[q].x, a.x); a.y = fmaf(yq, zq[q].y, a.y);
      a.z = fmaf(yq, zq[q].z, a.z); a.w = fmaf(yq, zq[q].w, a.w);
    }
    float4 o;
    o.x = a.x + (fabsf(v.x) > thr ? v.x : (mk.x ? fminf(fmaxf(rintf(v.x / sc), -128.f), 127.f) * sc : 0.f));
    o.y = a.y + (fabsf(v.y) > thr ? v.y : (mk.y ? fminf(fmaxf(rintf(v.y / sc), -128.f), 127.f) * sc : 0.f));
    o.z = a.z + (fabsf(v.z) > thr ? v.z : (mk.z ? fminf(fmaxf(rintf(v.z / sc), -128.f), 127.f) * sc : 0.f));
    o.w = a.w + (fabsf(v.w) > thr ? v.w : (mk.w ? fminf(fmaxf(rintf(v.w / sc), -128.f), 127.f) * sc : 0.f));
    *(float4*)(out1 + (size_t)rowu * D_ + d0 + dl) = o;
  }
}

// ---------------- launcher ----------------
extern "C" void kernel_launch(void* const* d_in, const int* in_sizes, int n_in,
                              void* d_out, int out_size, void* d_ws, size_t ws_size,
                              hipStream_t stream) {
  (void)in_sizes; (void)n_in; (void)out_size; (void)d_ws; (void)ws_size;
  const float* x = (const float*)d_in[0];
  float* out = (float*)d_out;
  float* out0    = out;
  float* out1    = out + TOT;
  float* o_outl  = out + 2 * TOT;
  float* o_scale = out + 2 * TOT + 1;

  hipLaunchKernelGGL(k_init,  dim3(1),   dim3(256), 0, stream);
  hipLaunchKernelGGL(k_pass1, dim3(512), dim3(256), 0, stream, x, out0);
  hipLaunchKernelGGL(k_scan,  dim3(1),   dim3(256), 0, stream, 0, o_outl);
  hipLaunchKernelGGL(k_histL, dim3(128), dim3(256), 0, stream, x, 1);
  hipLaunchKernelGGL(k_scan,  dim3(1),   dim3(256), 0, stream, 1, o_outl);
  hipLaunchKernelGGL(k_histL, dim3(128), dim3(256), 0, stream, x, 2);
  hipLaunchKernelGGL(k_scan,  dim3(1),   dim3(256), 0, stream, 2, o_outl);
  hipLaunchKernelGGL(k_colsel, dim3(1),  dim3(1024), 0, stream);
  hipLaunchKernelGGL(k_omega, dim3(256), dim3(256), 0, stream);
  // Q0 = orth(A @ omega)
  hipLaunchKernelGGL(k_AB,     dim3(256), dim3(1024), 0, stream, x, 0);
  hipLaunchKernelGGL(k_gram,   dim3(64),  dim3(256),  0, stream, 0);
  hipLaunchKernelGGL(k_chol,   dim3(1),   dim3(256),  0, stream, 0, 64);
  hipLaunchKernelGGL(k_scaleQ, dim3(64),  dim3(256),  0, stream, 0);
  // power iteration 1: Q1 = orth(A^T Q0)  (+ scale max on this pass)
  hipLaunchKernelGGL(k_AtB,       dim3(256), dim3(1024), 0, stream, x, 1);
  hipLaunchKernelGGL(k_scalewrite, dim3(1),  dim3(64),   0, stream, o_scale);
  hipLaunchKernelGGL(k_gram,      dim3(16),  dim3(256),  0, stream, 1);
  hipLaunchKernelGGL(k_chol,      dim3(1),   dim3(256),  0, stream, 0, 16);
  hipLaunchKernelGGL(k_scaleQ,    dim3(16),  dim3(256),  0, stream, 1);
  //                    Q2 = orth(A Q1)
  hipLaunchKernelGGL(k_AB,     dim3(256), dim3(1024), 0, stream, x, 1);
  hipLaunchKernelGGL(k_gram,   dim3(64),  dim3(256),  0, stream, 0);
  hipLaunchKernelGGL(k_chol,   dim3(1),   dim3(256),  0, stream, 0, 64);
  hipLaunchKernelGGL(k_scaleQ, dim3(64),  dim3(256),  0, stream, 0);
  // power iteration 2: Q3 = orth(A^T Q2)
  hipLaunchKernelGGL(k_AtB,    dim3(256), dim3(1024), 0, stream, x, 0);
  hipLaunchKernelGGL(k_gram,   dim3(16),  dim3(256),  0, stream, 1);
  hipLaunchKernelGGL(k_chol,   dim3(1),   dim3(256),  0, stream, 0, 16);
  hipLaunchKernelGGL(k_scaleQ, dim3(16),  dim3(256),  0, stream, 1);
  //                    Y4 = A Q3 ; Ginv = (Y4^T Y4)^-1
  hipLaunchKernelGGL(k_AB,     dim3(256), dim3(1024), 0, stream, x, 1);
  hipLaunchKernelGGL(k_gram,   dim3(64),  dim3(256),  0, stream, 0);
  hipLaunchKernelGGL(k_chol,   dim3(1),   dim3(256),  0, stream, 1, 64);
  // W = Y4^T A ; Z = Ginv W ; out1 = Y4 Z + outliers + quant
  hipLaunchKernelGGL(k_AtB,    dim3(256), dim3(1024), 0, stream, x, 0);
  hipLaunchKernelGGL(k_Zsolve, dim3(16),  dim3(256),  0, stream);
  hipLaunchKernelGGL(k_final,  dim3(64, 8), dim3(256), 0, stream, x, out1);
}

// Round 6
// 1086.246 us; speedup vs baseline: 1.5636x; 1.5636x over previous
//
#include <hip/hip_runtime.h>
#include <math.h>

#define D_   4096
#define N_   16384               // 8*2048 rows
#define TOT  67108864ULL         // N_*D_
#define KSEL 8304721u            // int(8388608*0.99), 1-indexed kth smallest

// ---------------- static device scratch ----------------
__device__ unsigned long long g_colsum[D_];     // fixed-point 2^32 column |x| sums
__device__ unsigned int  g_hist[2048];
__device__ unsigned int  g_state[2];            // {krem, prefix}
__device__ float         g_outliner;
__device__ unsigned int  g_maxbits;
__device__ float         g_scale;
__device__ unsigned char g_mask[D_];
__device__ float g_omega[D_ * 16];
__device__ float g_tall [N_ * 16];              // Y0 -> Q0 -> Y2 -> Q2 -> Y4
__device__ float g_small[D_ * 16];              // Y1 -> Q1 -> Y3 -> Q3 -> W -> Z
__device__ float g_part [16777216];             // 64MB split-K partial sums
__device__ float g_gpart[256 * 256];
__device__ float g_M[256];                      // L^-1 or G^-1 (fp32)

// ---------------- helpers ----------------
__device__ __forceinline__ unsigned rotl32(unsigned v, int s) { return (v << s) | (v >> (32 - s)); }

__device__ __forceinline__ float erfinv32(float xx) {   // XLA/Giles ErfInv32 polynomial
  float w = -log1pf(-xx * xx);
  float p;
  if (w < 5.f) {
    w -= 2.5f;
    p = 2.81022636e-08f;
    p = fmaf(p, w, 3.43273939e-07f);
    p = fmaf(p, w, -3.5233877e-06f);
    p = fmaf(p, w, -4.39150654e-06f);
    p = fmaf(p, w, 0.00021858087f);
    p = fmaf(p, w, -0.00125372503f);
    p = fmaf(p, w, -0.00417768164f);
    p = fmaf(p, w, 0.246640727f);
    p = fmaf(p, w, 1.50140941f);
  } else {
    w = sqrtf(w) - 3.f;
    p = -0.000200214257f;
    p = fmaf(p, w, 0.000100950558f);
    p = fmaf(p, w, 0.00134934322f);
    p = fmaf(p, w, -0.00367342844f);
    p = fmaf(p, w, 0.00573950773f);
    p = fmaf(p, w, -0.0076224613f);
    p = fmaf(p, w, 0.00943887047f);
    p = fmaf(p, w, 1.00167406f);
    p = fmaf(p, w, 2.83297682f);
  }
  return p * xx;
}

__device__ __forceinline__ float bits_to_normal(unsigned b) {
  float f = __uint_as_float((b >> 9) | 0x3f800000u) - 1.0f;
  float u = fmaf(f, 2.0f, -0.99999994f);
  u = fmaxf(-0.99999994f, u);
  return 1.41421356f * erfinv32(u);
}

__device__ __forceinline__ float gelu_exact(float v) {
  return 0.5f * v * (1.f + erff(v * 0.70710678f));
}

// ---------------- kernels ----------------
__global__ void k_init() {
  int t = threadIdx.x;
  for (int i = t; i < D_; i += 256) g_colsum[i] = 0ull;
  for (int i = t; i < 2048; i += 256) g_hist[i] = 0u;
  if (t == 0) { g_state[0] = KSEL; g_state[1] = 0u; g_maxbits = 0u; }
}

// pass1: gelu -> out0, fixed-point column sums, level-0 histogram of |x[0]|
__global__ __launch_bounds__(256) void k_pass1(const float* __restrict__ x, float* __restrict__ out0) {
  __shared__ unsigned lh[4 * 2056];             // 4 wave-private bank-shifted copies
  int t = threadIdx.x, b = blockIdx.x;
  bool doh = (b < 64);                      // blocks 0..63 cover rows 0..2047 = x[0]
  for (int i = t; i < 4 * 2056; i += 256) lh[i] = 0u;
  int cp = (t >> 6) * 2056;
  float acc[16];
#pragma unroll
  for (int j = 0; j < 16; ++j) acc[j] = 0.f;
  __syncthreads();
  const float4* xv = (const float4*)(x + (size_t)b * 131072);   // 32 rows
  float4* ov = (float4*)(out0 + (size_t)b * 131072);
  for (int i = 0; i < 128; i += 4) {
#pragma unroll
    for (int jj = 0; jj < 4; ++jj) {
      int f = t + 256 * (i + jj);
      float4 v = xv[f];
      float4 g;
      g.x = gelu_exact(v.x); g.y = gelu_exact(v.y); g.z = gelu_exact(v.z); g.w = gelu_exact(v.w);
      ov[f] = g;
      acc[jj * 4 + 0] += fabsf(v.x);
      acc[jj * 4 + 1] += fabsf(v.y);
      acc[jj * 4 + 2] += fabsf(v.z);
      acc[jj * 4 + 3] += fabsf(v.w);
      if (doh) {
        atomicAdd(&lh[cp + ((__float_as_uint(v.x) & 0x7fffffffu) >> 21)], 1u);
        atomicAdd(&lh[cp + ((__float_as_uint(v.y) & 0x7fffffffu) >> 21)], 1u);
        atomicAdd(&lh[cp + ((__float_as_uint(v.z) & 0x7fffffffu) >> 21)], 1u);
        atomicAdd(&lh[cp + ((__float_as_uint(v.w) & 0x7fffffffu) >> 21)], 1u);
      }
    }
  }
#pragma unroll
  for (int jj = 0; jj < 4; ++jj) {
    int c4 = t + 256 * jj;
#pragma unroll
    for (int k = 0; k < 4; ++k) {
      unsigned long long q = (unsigned long long)((double)acc[jj * 4 + k] * 4294967296.0 + 0.5);
      atomicAdd(&g_colsum[4 * c4 + k], q);
    }
  }
  if (doh) {
    __syncthreads();
    for (int i = t; i < 2048; i += 256) {
      unsigned c = lh[i] + lh[2056 + i] + lh[4112 + i] + lh[6168 + i];
      if (c) atomicAdd(&g_hist[i], c);
    }
  }
}

// radix-select refinement histograms over x[0] (level 1: mid 11 bits, level 2: low 10 bits)
__global__ __launch_bounds__(256) void k_histL(const float* __restrict__ x, int level) {
  __shared__ unsigned lh[2048];
  int t = threadIdx.x, b = blockIdx.x;
  for (int i = t; i < 2048; i += 256) lh[i] = 0u;
  __syncthreads();
  unsigned pre = g_state[1];
  const float4* xv = (const float4*)x;
  size_t base = (size_t)b * 16384;
  for (int i = 0; i < 64; ++i) {
    float4 v = xv[base + t + 256 * i];
    unsigned u;
#define HPROC(comp) \
    u = __float_as_uint(comp) & 0x7fffffffu; \
    if (level == 1) { if ((u >> 21) == (pre >> 21)) atomicAdd(&lh[(u >> 10) & 0x7ffu], 1u); } \
    else            { if ((u >> 10) == (pre >> 10)) atomicAdd(&lh[u & 0x3ffu], 1u); }
    HPROC(v.x) HPROC(v.y) HPROC(v.z) HPROC(v.w)
#undef HPROC
  }
  __syncthreads();
  for (int i = t; i < 2048; i += 256) { unsigned c = lh[i]; if (c) atomicAdd(&g_hist[i], c); }
}

__global__ void k_scan(int level, float* __restrict__ od) {
  __shared__ unsigned h[2048];
  __shared__ unsigned ps[256];
  int t = threadIdx.x;
  unsigned loc = 0;
#pragma unroll
  for (int i = 0; i < 8; ++i) { unsigned v = g_hist[t * 8 + i]; h[t * 8 + i] = v; loc += v; }
  ps[t] = loc;
  __syncthreads();
  if (t == 0) {
    unsigned krem = g_state[0], pre = g_state[1];
    unsigned cum = 0; int g = 0;
    for (; g < 255; ++g) { if (cum + ps[g] >= krem) break; cum += ps[g]; }
    int b = g * 8;
    for (; b < 2047; ++b) { if (cum + h[b] >= krem) break; cum += h[b]; }
    krem -= cum;
    if (level == 0)      pre = ((unsigned)b) << 21;
    else if (level == 1) pre |= ((unsigned)b) << 10;
    else { pre |= (unsigned)b; g_outliner = __uint_as_float(pre); od[0] = __uint_as_float(pre); }
    g_state[0] = krem; g_state[1] = pre;
  }
  __syncthreads();
  for (int i = t; i < 2048; i += 256) g_hist[i] = 0u;
}

// top-819 column threshold via in-LDS bitonic sort of the 4096 fixed-point sums
__global__ __launch_bounds__(1024) void k_colsel() {
  __shared__ unsigned long long s[4096];
  int t = threadIdx.x;
  for (int m = 0; m < 4; ++m) s[t + 1024 * m] = g_colsum[t + 1024 * m];
  __syncthreads();
  for (int k = 2; k <= 4096; k <<= 1) {
    for (int j = k >> 1; j > 0; j >>= 1) {
#pragma unroll
      for (int m = 0; m < 4; ++m) {
        int i = t + 1024 * m;
        int l = i ^ j;
        if (l > i) {
          unsigned long long a = s[i], c = s[l];
          bool up = ((i & k) == 0);
          if (up ? (a > c) : (a < c)) { s[i] = c; s[l] = a; }
        }
      }
      __syncthreads();
    }
  }
  unsigned long long T = s[4096 - 819];
  for (int m = 0; m < 4; ++m) { int i = t + 1024 * m; g_mask[i] = (g_colsum[i] >= T) ? 1 : 0; }
}

// omega = jax.random.normal(key(42), (4096,16)), partitionable threefry counter mode
__global__ void k_omega() {
  unsigned i = blockIdx.x * 256 + threadIdx.x;
  if (i >= 65536u) return;
  const unsigned ks0 = 0u, ks1 = 42u, ks2 = 0x1BD11BDAu ^ 42u;
  unsigned x0 = 0u + ks0;
  unsigned x1 = i  + ks1;
#define RND(r) { x0 += x1; x1 = rotl32(x1, r); x1 ^= x0; }
  RND(13) RND(15) RND(26) RND(6)   x0 += ks1; x1 += ks2 + 1u;
  RND(17) RND(29) RND(16) RND(24)  x0 += ks2; x1 += ks0 + 2u;
  RND(13) RND(15) RND(26) RND(6)   x0 += ks0; x1 += ks1 + 3u;
  RND(17) RND(29) RND(16) RND(24)  x0 += ks1; x1 += ks2 + 4u;
  RND(13) RND(15) RND(26) RND(6)   x0 += ks2; x1 += ks0 + 5u;
#undef RND
  g_omega[i] = bits_to_normal(x0 ^ x1);
}

// Y = A @ B  (A = masked x on the fly, B = omega or g_small), split-K partials.
// grid (64 rowblocks, 16 ksplits), block 256 — round-3 coalesced version.
__global__ __launch_bounds__(256) void k_AB(const float* __restrict__ x, int bsel) {
  __shared__ float xt[256 * 33];
  int t = threadIdx.x;
  int rb = blockIdx.x, ks = blockIdx.y;
  const float* Bm = bsel ? g_small : g_omega;
  float thr = g_outliner;
  float acc[16];
#pragma unroll
  for (int q = 0; q < 16; ++q) acc[q] = 0.f;
  int row0 = rb * 256;
  for (int ch = 0; ch < 8; ++ch) {
    int d0 = ks * 256 + ch * 32;
#pragma unroll
    for (int m = 0; m < 8; ++m) {
      int f = t + 256 * m;               // 0..2047 float4 slots (256 rows x 8)
      int r = f >> 3, c4 = f & 7;
      float4 v = *(const float4*)(x + (size_t)(row0 + r) * D_ + d0 + 4 * c4);
      uchar4 mk = *(const uchar4*)(g_mask + d0 + 4 * c4);
      float a0 = (mk.x || fabsf(v.x) > thr) ? 0.f : v.x;
      float a1 = (mk.y || fabsf(v.y) > thr) ? 0.f : v.y;
      float a2 = (mk.z || fabsf(v.z) > thr) ? 0.f : v.z;
      float a3 = (mk.w || fabsf(v.w) > thr) ? 0.f : v.w;
      int base = r * 33 + 4 * c4;
      xt[base + 0] = a0; xt[base + 1] = a1; xt[base + 2] = a2; xt[base + 3] = a3;
    }
    __syncthreads();
    for (int d = 0; d < 32; ++d) {
      const float* br = Bm + (size_t)(d0 + d) * 16;
      float a0 = xt[t * 33 + d];
#pragma unroll
      for (int q = 0; q < 16; ++q) acc[q] = fmaf(a0, br[q], acc[q]);
    }
    __syncthreads();
  }
  float* p0 = g_part + ((size_t)ks * N_ + row0 + t) * 16;
#pragma unroll
  for (int q4 = 0; q4 < 4; ++q4)
    *(float4*)(p0 + 4 * q4) = make_float4(acc[4*q4], acc[4*q4+1], acc[4*q4+2], acc[4*q4+3]);
}

// Y = A^T @ B  (B = g_tall). grid 256 blocks x 64 rows, block 1024 (thread owns 4 cols).
// round-3 coalesced version.
__global__ __launch_bounds__(1024) void k_AtB(const float* __restrict__ x, int do_max) {
  __shared__ float wm[16];
  int t = threadIdx.x, b = blockIdx.x;
  float thr = g_outliner;
  uchar4 mk = *(const uchar4*)(g_mask + 4 * t);
  float acc[4][16];
#pragma unroll
  for (int j = 0; j < 4; ++j)
#pragma unroll
    for (int q = 0; q < 16; ++q) acc[j][q] = 0.f;
  float mx = 0.f;
  size_t row0 = (size_t)b * 64;
  for (int r = 0; r < 64; ++r) {
    size_t row = row0 + r;
    float4 v = *(const float4*)(x + row * D_ + 4 * t);
    const float* br = g_tall + row * 16;
    float ax = fabsf(v.x), ay = fabsf(v.y), az = fabsf(v.z), aw = fabsf(v.w);
    float a0 = (mk.x || ax > thr) ? 0.f : v.x;
    float a1 = (mk.y || ay > thr) ? 0.f : v.y;
    float a2 = (mk.z || az > thr) ? 0.f : v.z;
    float a3 = (mk.w || aw > thr) ? 0.f : v.w;
    if (do_max) {
      if (mk.x && ax <= thr) mx = fmaxf(mx, ax);
      if (mk.y && ay <= thr) mx = fmaxf(mx, ay);
      if (mk.z && az <= thr) mx = fmaxf(mx, az);
      if (mk.w && aw <= thr) mx = fmaxf(mx, aw);
    }
#pragma unroll
    for (int q = 0; q < 16; ++q) {
      float bq = br[q];
      acc[0][q] = fmaf(a0, bq, acc[0][q]);
      acc[1][q] = fmaf(a1, bq, acc[1][q]);
      acc[2][q] = fmaf(a2, bq, acc[2][q]);
      acc[3][q] = fmaf(a3, bq, acc[3][q]);
    }
  }
  float* pb = g_part + ((size_t)b * D_ + 4 * t) * 16;
#pragma unroll
  for (int j = 0; j < 4; ++j)
#pragma unroll
    for (int q4 = 0; q4 < 4; ++q4)
      *(float4*)(pb + j * 16 + 4 * q4) =
        make_float4(acc[j][4*q4], acc[j][4*q4+1], acc[j][4*q4+2], acc[j][4*q4+3]);
  if (do_max) {
#pragma unroll
    for (int off = 32; off > 0; off >>= 1) mx = fmaxf(mx, __shfl_xor(mx, off, 64));
    if ((t & 63) == 0) wm[t >> 6] = mx;
    __syncthreads();
    if (t == 0) {
      float m2 = wm[0];
      for (int i = 1; i < 16; ++i) m2 = fmaxf(m2, wm[i]);
      atomicMax(&g_maxbits, __float_as_uint(m2));
    }
  }
}

// FUSED combine(mode0)+gram(which0): grid 256, block 256. Block owns 64 rows of Y.
// Combines the 16 split-K partials (coalesced), writes g_tall, Gram partial in LDS.
__global__ __launch_bounds__(256) void k_combG0() {
  __shared__ float ys[1024];                    // 64 rows x 16
  int t = threadIdx.x, blk = blockIdx.x;
#pragma unroll
  for (int m = 0; m < 4; ++m) {
    int j = blk * 1024 + m * 256 + t;           // float index into Y [0, 262144)
    float s = 0.f;
    for (int k2 = 0; k2 < 16; ++k2) s += g_part[k2 * 262144 + j];
    g_tall[j] = s;
    ys[m * 256 + t] = s;
  }
  __syncthreads();
  int a = t >> 4, b = t & 15;
  float acc = 0.f;
  for (int r = 0; r < 64; ++r) acc = fmaf(ys[r * 16 + a], ys[r * 16 + b], acc);
  g_gpart[blk * 256 + t] = acc;
}

// FUSED combine(mode1)+gram(which1)+optional scalewrite: grid 256, block 256.
// Block owns 16 rows of W/Y'. 256 split parts summed (coalesced scalar loads).
__global__ __launch_bounds__(256) void k_combG1(int do_scale, float* __restrict__ od) {
  __shared__ float ys[256];                     // 16 rows x 16
  int t = threadIdx.x, blk = blockIdx.x;
  int j = blk * 256 + t;                        // float index into Y' [0, 65536)
  float s = 0.f;
  for (int k2 = 0; k2 < 256; ++k2) s += g_part[k2 * 65536 + j];
  g_small[j] = s;
  ys[t] = s;
  if (do_scale && blk == 0 && t == 0) {
    float sc = __uint_as_float(g_maxbits) / 127.0f;
    g_scale = sc; od[0] = sc;
  }
  __syncthreads();
  int a = t >> 4, b = t & 15;
  float acc = 0.f;
  for (int r = 0; r < 16; ++r) acc = fmaf(ys[r * 16 + a], ys[r * 16 + b], acc);
  g_gpart[blk * 256 + t] = acc;
}

// combine Gram partials (np=256), Cholesky (fp64): mode 0 -> g_M = L^-1 ; mode 1 -> g_M = G^-1
__global__ void k_chol(int mode) {
  __shared__ double G[256], L[256], M[256];
  int t = threadIdx.x;
  double s = 0.0;
  for (int p = 0; p < 256; ++p) s += (double)g_gpart[p * 256 + t];
  G[t] = s; M[t] = 0.0; L[t] = 0.0;
  __syncthreads();
  for (int j = 0; j < 16; ++j) {
    if (t == j) {
      double d = G[j * 16 + j];
      for (int k = 0; k < j; ++k) d -= L[j * 16 + k] * L[j * 16 + k];
      L[j * 16 + j] = sqrt(d);
    }
    __syncthreads();
    if (t > j && t < 16) {
      double d = G[t * 16 + j];
      for (int k = 0; k < j; ++k) d -= L[t * 16 + k] * L[j * 16 + k];
      L[t * 16 + j] = d / L[j * 16 + j];
    }
    __syncthreads();
  }
  if (t < 16) {                      // column t of M = L^-1
    int jc = t;
    M[jc * 16 + jc] = 1.0 / L[jc * 16 + jc];
    for (int i2 = jc + 1; i2 < 16; ++i2) {
      double s2 = 0.0;
      for (int k = jc; k < i2; ++k) s2 += L[i2 * 16 + k] * M[k * 16 + jc];
      M[i2 * 16 + jc] = -s2 / L[i2 * 16 + i2];
    }
  }
  __syncthreads();
  if (mode == 0) g_M[t] = (float)M[t];
  else {
    int i2 = t >> 4, j2 = t & 15;
    double s2 = 0.0;
    for (int k = 0; k < 16; ++k) s2 += M[k * 16 + i2] * M[k * 16 + j2];
    g_M[t] = (float)s2;              // G^-1 = M^T M
  }
}

// Q = Y * L^-T in place: q[j] = sum_{i<=j} M[j][i]*y[i]
__global__ __launch_bounds__(256) void k_scaleQ(int which) {
  __shared__ float Mf[256];
  float* Y = which ? g_small : g_tall;
  int t = threadIdx.x;
  Mf[t] = g_M[t];
  __syncthreads();
  size_t row = (size_t)blockIdx.x * 256 + t;
  float4* yr = (float4*)(Y + row * 16);
  float4 v0 = yr[0], v1 = yr[1], v2 = yr[2], v3 = yr[3];
  float y[16] = {v0.x,v0.y,v0.z,v0.w, v1.x,v1.y,v1.z,v1.w, v2.x,v2.y,v2.z,v2.w, v3.x,v3.y,v3.z,v3.w};
  float q[16];
#pragma unroll
  for (int jq = 0; jq < 16; ++jq) {
    float s = 0.f;
    for (int iq = 0; iq <= jq; ++iq) s = fmaf(Mf[jq * 16 + iq], y[iq], s);
    q[jq] = s;
  }
  yr[0] = make_float4(q[0],q[1],q[2],q[3]);
  yr[1] = make_float4(q[4],q[5],q[6],q[7]);
  yr[2] = make_float4(q[8],q[9],q[10],q[11]);
  yr[3] = make_float4(q[12],q[13],q[14],q[15]);
}

// Z[d] = Ginv * W[d] in place in g_small
__global__ __launch_bounds__(256) void k_Zsolve() {
  __shared__ float Gf[256];
  int t = threadIdx.x;
  Gf[t] = g_M[t];
  __syncthreads();
  size_t d = (size_t)blockIdx.x * 256 + t;
  float4* wr = (float4*)(g_small + d * 16);
  float4 v0 = wr[0], v1 = wr[1], v2 = wr[2], v3 = wr[3];
  float w[16] = {v0.x,v0.y,v0.z,v0.w, v1.x,v1.y,v1.z,v1.w, v2.x,v2.y,v2.z,v2.w, v3.x,v3.y,v3.z,v3.w};
  float z[16];
#pragma unroll
  for (int jq = 0; jq < 16; ++jq) {
    float s = 0.f;
#pragma unroll
    for (int iq = 0; iq < 16; ++iq) s = fmaf(Gf[jq * 16 + iq], w[iq], s);
    z[jq] = s;
  }
  wr[0] = make_float4(z[0],z[1],z[2],z[3]);
  wr[1] = make_float4(z[4],z[5],z[6],z[7]);
  wr[2] = make_float4(z[8],z[9],z[10],z[11]);
  wr[3] = make_float4(z[12],z[13],z[14],z[15]);
}

// out1 = Y4 @ Z + outliers + quantized sub-outlier cols. grid (64 rowblocks, 8 col panels).
__global__ __launch_bounds__(256) void k_final(const float* __restrict__ x, float* __restrict__ out1) {
  __shared__ float zt[16 * 516];     // Z^T panel [q][512] staging (coalesced global load)
  int t = threadIdx.x;
  int rb = blockIdx.x, pn = blockIdx.y;
  int d0 = pn * 512;
  int row0 = rb * 256;
#pragma unroll
  for (int i = 0; i < 8; ++i) {
    int f = t + 256 * i;             // 0..2047
    int dd = f >> 2, q4 = f & 3;
    float4 zv = *(const float4*)(g_small + (size_t)(d0 + dd) * 16 + 4 * q4);
    zt[(4 * q4 + 0) * 516 + dd] = zv.x;
    zt[(4 * q4 + 1) * 516 + dd] = zv.y;
    zt[(4 * q4 + 2) * 516 + dd] = zv.z;
    zt[(4 * q4 + 3) * 516 + dd] = zv.w;
  }
  __syncthreads();
  float thr = g_outliner, sc = g_scale;
  int lf = t & 127;
  int half = t >> 7;
  int dl = 4 * lf;
  float4 zq[16];
#pragma unroll
  for (int q = 0; q < 16; ++q) zq[q] = *(const float4*)&zt[q * 516 + dl];
  uchar4 mk = *(const uchar4*)(g_mask + d0 + dl);
  for (int i = 0; i < 128; ++i) {
    int row = row0 + 2 * i + half;
    int rowu = __builtin_amdgcn_readfirstlane(row);   // wave-uniform by construction
    const float* yr = g_tall + (size_t)rowu * 16;
    float4 v = *(const float4*)(x + (size_t)rowu * D_ + d0 + dl);
    float4 a = make_float4(0.f, 0.f, 0.f, 0.f);
#pragma unroll
    for (int q = 0; q < 16; ++q) {
      float yq = yr[q];
      a.x = fmaf(yq, zq[q].x, a.x); a.y = fmaf(yq, zq[q].y, a.y);
      a.z = fmaf(yq, zq[q].z, a.z); a.w = fmaf(yq, zq[q].w, a.w);
    }
    float4 o;
    o.x = a.x + (fabsf(v.x) > thr ? v.x : (mk.x ? fminf(fmaxf(rintf(v.x / sc), -128.f), 127.f) * sc : 0.f));
    o.y = a.y + (fabsf(v.y) > thr ? v.y : (mk.y ? fminf(fmaxf(rintf(v.y / sc), -128.f), 127.f) * sc : 0.f));
    o.z = a.z + (fabsf(v.z) > thr ? v.z : (mk.z ? fminf(fmaxf(rintf(v.z / sc), -128.f), 127.f) * sc : 0.f));
    o.w = a.w + (fabsf(v.w) > thr ? v.w : (mk.w ? fminf(fmaxf(rintf(v.w / sc), -128.f), 127.f) * sc : 0.f));
    *(float4*)(out1 + (size_t)rowu * D_ + d0 + dl) = o;
  }
}

// ---------------- launcher ----------------
extern "C" void kernel_launch(void* const* d_in, const int* in_sizes, int n_in,
                              void* d_out, int out_size, void* d_ws, size_t ws_size,
                              hipStream_t stream) {
  (void)in_sizes; (void)n_in; (void)out_size; (void)d_ws; (void)ws_size;
  const float* x = (const float*)d_in[0];
  float* out = (float*)d_out;
  float* out0    = out;
  float* out1    = out + TOT;
  float* o_outl  = out + 2 * TOT;
  float* o_scale = out + 2 * TOT + 1;

  hipLaunchKernelGGL(k_init,  dim3(1),   dim3(256), 0, stream);
  hipLaunchKernelGGL(k_pass1, dim3(512), dim3(256), 0, stream, x, out0);
  hipLaunchKernelGGL(k_scan,  dim3(1),   dim3(256), 0, stream, 0, o_outl);
  hipLaunchKernelGGL(k_histL, dim3(128), dim3(256), 0, stream, x, 1);
  hipLaunchKernelGGL(k_scan,  dim3(1),   dim3(256), 0, stream, 1, o_outl);
  hipLaunchKernelGGL(k_histL, dim3(128), dim3(256), 0, stream, x, 2);
  hipLaunchKernelGGL(k_scan,  dim3(1),   dim3(256), 0, stream, 2, o_outl);
  hipLaunchKernelGGL(k_colsel, dim3(1),  dim3(1024), 0, stream);
  hipLaunchKernelGGL(k_omega, dim3(256), dim3(256), 0, stream);
  // stage 1: Q0 = orth(A @ omega)
  hipLaunchKernelGGL(k_AB,     dim3(64, 16), dim3(256), 0, stream, x, 0);
  hipLaunchKernelGGL(k_combG0, dim3(256),    dim3(256), 0, stream);
  hipLaunchKernelGGL(k_chol,   dim3(1),      dim3(256), 0, stream, 0);
  hipLaunchKernelGGL(k_scaleQ, dim3(64),     dim3(256), 0, stream, 0);
  // stage 2: Q1 = orth(A^T Q0)  (+ scale from this pass's max)
  hipLaunchKernelGGL(k_AtB,    dim3(256), dim3(1024), 0, stream, x, 1);
  hipLaunchKernelGGL(k_combG1, dim3(256), dim3(256),  0, stream, 1, o_scale);
  hipLaunchKernelGGL(k_chol,   dim3(1),   dim3(256),  0, stream, 0);
  hipLaunchKernelGGL(k_scaleQ, dim3(16),  dim3(256),  0, stream, 1);
  // stage 3: Q2 = orth(A Q1)
  hipLaunchKernelGGL(k_AB,     dim3(64, 16), dim3(256), 0, stream, x, 1);
  hipLaunchKernelGGL(k_combG0, dim3(256),    dim3(256), 0, stream);
  hipLaunchKernelGGL(k_chol,   dim3(1),      dim3(256), 0, stream, 0);
  hipLaunchKernelGGL(k_scaleQ, dim3(64),     dim3(256), 0, stream, 0);
  // stage 4: Q3 = orth(A^T Q2)
  hipLaunchKernelGGL(k_AtB,    dim3(256), dim3(1024), 0, stream, x, 0);
  hipLaunchKernelGGL(k_combG1, dim3(256), dim3(256),  0, stream, 0, o_scale);
  hipLaunchKernelGGL(k_chol,   dim3(1),   dim3(256),  0, stream, 0);
  hipLaunchKernelGGL(k_scaleQ, dim3(16),  dim3(256),  0, stream, 1);
  // stage 5: Y4 = A Q3 ; Ginv = (Y4^T Y4)^-1
  hipLaunchKernelGGL(k_AB,     dim3(64, 16), dim3(256), 0, stream, x, 1);
  hipLaunchKernelGGL(k_combG0, dim3(256),    dim3(256), 0, stream);
  hipLaunchKernelGGL(k_chol,   dim3(1),      dim3(256), 0, stream, 1);
  // stage 6: W = Y4^T A ; Z = Ginv W ; out1 = Y4 Z + outliers + quant
  hipLaunchKernelGGL(k_AtB,    dim3(256), dim3(1024), 0, stream, x, 0);
  hipLaunchKernelGGL(k_combG1, dim3(256), dim3(256),  0, stream, 0, o_scale);
  hipLaunchKernelGGL(k_Zsolve, dim3(16),  dim3(256),  0, stream);
  hipLaunchKernelGGL(k_final,  dim3(64, 8), dim3(256), 0, stream, x, out1);
}